// Round 3
// baseline (206.926 us; speedup 1.0000x reference)
//
#include <hip/hip_runtime.h>
#include <hip/hip_bf16.h>
#include <stdint.h>

// CortexBlock — reference collapses (U,V start at 0; update is multiplicative
// in the state, so the fast-weight path is identically 0):
//   y[row,h,:] = sigmoid((q_h.k_h)/8) * v_h ;  out = y @ Wo^T
// Round 11: gemm_qkv: fix r10's two measured failures:
//  (1) 4.7M bank conflicts: BK=32 b128 reads were 8-way conflicted
//      (bank = 16*(row&1)+4*quad). Fix: r8's XOR swizzle, both sides:
//      read chunk rc = quad ^ ((l16>>1)&3); DMA source pre-swizzled
//      gch = (l&3)^((l>>3)&3) with linear LDS dest (rule #21).
//  (2) Occupancy 15% (~1.2 blocks/CU): 72 KiB LDS capped residency at 2.
//      Fix: BM=BN=128, BK=32, triple-buf = 48 KiB -> 3 blocks/CU, grid
//      64x24 = 1536 jobs = 6/CU even. launch_bounds(256,3).
//  Keeps: DMA staging, counted vmcnt(4) (t+2 loads in flight across the
//  barrier), setprio around MFMA, XCD-chunked remap (1536 = 8*192).
// cast_kernel / gemm_out_kernel unchanged from round 8.
#define D_MODEL 1024
#define N_HEADS 16
#define D_HEAD  64
#define SEQ_T   2048
#define BATCH   4

typedef unsigned short u16;
typedef __bf16 bf16x8 __attribute__((ext_vector_type(8)));
typedef float  f32x4  __attribute__((ext_vector_type(4)));

#define NT 32          // K tiles for gemm_out (K=1024, BK=32)
#define BUF 4096       // u16 elements per LDS buffer (128*32) for gemm_out
#define QNT 32         // K tiles for gemm_qkv (K=1024, BK=32)

// ---- helpers ---------------------------------------------------------------
__device__ __forceinline__ u16 f2bf(float x) {  // RNE f32->bf16
  unsigned u = __float_as_uint(x);
  u += 0x7fffu + ((u >> 16) & 1u);
  return (u16)(u >> 16);
}
__device__ __forceinline__ unsigned pk2(float a, float b) {
  return (unsigned)f2bf(a) | ((unsigned)f2bf(b) << 16);
}
__device__ __forceinline__ unsigned scale2(unsigned p, float s) {
  float lo = __uint_as_float(p << 16) * s;
  float hi = __uint_as_float(p & 0xffff0000u) * s;
  return pk2(lo, hi);
}
// async global->LDS, 16B per lane; LDS dest must be wave-uniform base+lane*16.
__device__ __forceinline__ void cp16(const u16* g, u16* l) {
  __builtin_amdgcn_global_load_lds(
      (const __attribute__((address_space(1))) unsigned int*)g,
      (__attribute__((address_space(3))) unsigned int*)l, 16, 0, 0);
}

// ---- fused cast fp32 -> bf16 with weight-row remap, 32B/thread -------------
// Wb rows: [0,2048): qk-interleaved: row h*128 + jj*16 + l  (jj=0..7) =
//   (jj odd ? Wk : Wq)[h*64 + (jj>>1)*16 + l];  [2048,3072): Wv; [3072,4096): Wo.
__global__ __launch_bounds__(256) void cast_kernel(const float* __restrict__ hs,
                                                   const float* __restrict__ wq,
                                                   const float* __restrict__ wk,
                                                   const float* __restrict__ wv,
                                                   const float* __restrict__ wo,
                                                   u16* __restrict__ Xb,
                                                   u16* __restrict__ Wb) {
  int g = blockIdx.x * 256 + threadIdx.x;  // 8-float groups; 1.5M total
  const float4* src; uint4* dst;
  if (g < (1 << 20)) {                     // X: 1M groups
    src = (const float4*)hs + 2 * (size_t)g;
    dst = (uint4*)Xb + g;
  } else {
    int j = g - (1 << 20);                 // W: 512K groups, 128 per row
    int R = j >> 7;                        // dest row (block-uniform branch mix ok)
    int col8 = j & 127;
    const float* s;
    int srow;
    if (R < 2048) {
      int h = R >> 7, c = R & 127, jj = c >> 4, l = c & 15;
      srow = h * 64 + (jj >> 1) * 16 + l;
      s = (jj & 1) ? wk : wq;
    } else if (R < 3072) { s = wv; srow = R - 2048; }
    else                 { s = wo; srow = R - 3072; }
    src = (const float4*)s + (size_t)srow * 256 + col8 * 2;
    dst = (uint4*)Wb + (size_t)R * 128 + col8;
  }
  float4 lo = src[0], hi = src[1];
  uint4 o;
  o.x = pk2(lo.x, lo.y); o.y = pk2(lo.z, lo.w);
  o.z = pk2(hi.x, hi.y); o.w = pk2(hi.z, hi.w);
  *dst = o;
}

// ---- QKV GEMM: 128x128 tile, BK=32, triple-buffer DMA, swizzled LDS --------
// C[M, 3072-virtual] = X[M,1024] * Wb[qk|v][.,1024]^T, bf16 operands.
// LDS (u16 idx): A[3][128][32] at 0 (4096/buf), B[3][128][32] at 12288.
// Swizzle: LDS[r][c] holds global chunk c ^ ((r>>1)&3)  (16B chunks).
#define QVM(n) asm volatile("s_waitcnt vmcnt(" #n ")" ::: "memory")

__global__ __launch_bounds__(256, 3) void gemm_qkv_kernel(const u16* __restrict__ A,
                                                          const u16* __restrict__ B,
                                                          u16* __restrict__ Vb,
                                                          float* __restrict__ S) {
  __shared__ u16 Ls[24576];  // 48 KiB
  const int tid  = threadIdx.x;
  const int w    = tid >> 6;     // 4 waves
  const int l    = tid & 63;
  const int quad = l >> 4;
  const int l16  = l & 15;
  const int wm   = (w >> 1) * 64;    // wave row offset (2x2 of 64x64)
  const int wn   = (w & 1) * 64;     // wave col offset
  const int rc   = (quad ^ ((l16 >> 1) & 3)) * 8;  // swizzled read chunk (u16)

  // XCD-chunked work remap: 1536 = 8 chunks * 192 (8 bm panels per XCD).
  const int id  = blockIdx.y * 24 + blockIdx.x;
  const int id2 = (id & 7) * 192 + (id >> 3);
  const int bm  = id2 / 24;          // 0..63 (128-row panel)
  const int bn  = id2 % 24;          // 0..15 score (head bn), 16..23 v

  // ---- staging: pre-swizzled SOURCE, linear LDS dest (rule #21) ----
  const int srow = w * 16 + (l >> 2);              // 0..63 within 64-row unit
  const int gch  = ((l & 3) ^ ((l >> 3) & 3)) * 8; // swizzled src chunk (u16)
  const u16* aS[2]; const u16* bS[2];
  #pragma unroll
  for (int u = 0; u < 2; ++u) {
    aS[u] = A + (size_t)(bm * 128 + u * 64 + srow) * 1024 + gch;
    bS[u] = B + (size_t)(bn * 128 + u * 64 + srow) * 1024 + gch;
  }
  u16* dst = Ls + w * 512 + l * 8;   // + sbuf*4096 + u*2048 (+12288 for B)

  f32x4 acc[4][4];
  #pragma unroll
  for (int i = 0; i < 4; ++i)
    #pragma unroll
    for (int j = 0; j < 4; ++j) acc[i][j] = (f32x4){0.f, 0.f, 0.f, 0.f};

  // ---- prologue: stage tiles 0,1; wait tile 0 only ----
  #pragma unroll
  for (int u = 0; u < 2; ++u) cp16(aS[u] + 0, dst + u * 2048);
  #pragma unroll
  for (int u = 0; u < 2; ++u) cp16(bS[u] + 0, dst + 12288 + u * 2048);
  #pragma unroll
  for (int u = 0; u < 2; ++u) cp16(aS[u] + 32, dst + 4096 + u * 2048);
  #pragma unroll
  for (int u = 0; u < 2; ++u) cp16(bS[u] + 32, dst + 16384 + u * 2048);
  QVM(4);
  __builtin_amdgcn_s_barrier();

  // ---- main loop: 1 K-tile (BK=32) per iteration ----
  int rbuf = 0, sbuf = 2;
  #pragma unroll 1
  for (int t = 0; t < QNT; ++t) {
    if (t + 2 < QNT) {  // stage tile t+2 into sbuf (4 cp16)
      const int o = (t + 2) * 32;
      cp16(aS[0] + o, dst + sbuf * 4096);
      cp16(aS[1] + o, dst + sbuf * 4096 + 2048);
      cp16(bS[0] + o, dst + 12288 + sbuf * 4096);
      cp16(bS[1] + o, dst + 12288 + sbuf * 4096 + 2048);
    }
    const u16* Ar = Ls + rbuf * 4096;
    const u16* Br = Ls + 12288 + rbuf * 4096;
    bf16x8 af[4], bfr[4];
    #pragma unroll
    for (int i = 0; i < 4; ++i)
      af[i] = *(const bf16x8*)(Ar + (wm + i * 16 + l16) * 32 + rc);
    #pragma unroll
    for (int j = 0; j < 4; ++j)
      bfr[j] = *(const bf16x8*)(Br + (wn + j * 16 + l16) * 32 + rc);
    __builtin_amdgcn_s_setprio(1);
    #pragma unroll
    for (int i = 0; i < 4; ++i)
      #pragma unroll
      for (int j = 0; j < 4; ++j)
        acc[i][j] = __builtin_amdgcn_mfma_f32_16x16x32_bf16(af[i], bfr[j], acc[i][j], 0, 0, 0);
    __builtin_amdgcn_s_setprio(0);
    if (t + 2 < QNT) { QVM(4); } else { QVM(0); }
    __builtin_amdgcn_s_barrier();
    rbuf = (rbuf == 2) ? 0 : rbuf + 1;
    sbuf = (sbuf == 2) ? 0 : sbuf + 1;
  }

  // ---- epilogue ----
  if (bn < 16) {
    // one head per block (head bn): col c -> jj = c>>4 = (w&1)*4 + j;
    // (q,k) pairs are (j even, j odd); d-space split across wave columns.
    float part[4][4];
    #pragma unroll
    for (int i = 0; i < 4; ++i)
      #pragma unroll
      for (int e = 0; e < 4; ++e)
        part[i][e] = acc[i][0][e] * acc[i][1][e] + acc[i][2][e] * acc[i][3][e];
    #pragma unroll
    for (int m = 1; m <= 8; m <<= 1)
      #pragma unroll
      for (int i = 0; i < 4; ++i)
        #pragma unroll
        for (int e = 0; e < 4; ++e)
          part[i][e] += __shfl_xor(part[i][e], m);  // reduce over l16 (d-low)
    float* Sp = (float*)Ls;  // [128][2] f32
    if (l16 == 0) {
      #pragma unroll
      for (int i = 0; i < 4; ++i)
        #pragma unroll
        for (int e = 0; e < 4; ++e)
          Sp[(wm + i * 16 + quad * 4 + e) * 2 + (w & 1)] = part[i][e];
    }
    __syncthreads();
    if (tid < 128) {
      float s = (Sp[tid * 2] + Sp[tid * 2 + 1]) * 0.125f;  // 1/sqrt(64)
      S[(size_t)(bm * 128 + tid) * N_HEADS + bn] = 1.f / (1.f + __expf(-s));
    }
  } else {
    const int cb = (bn - 16) * 128;
    #pragma unroll
    for (int i = 0; i < 4; ++i)
      #pragma unroll
      for (int j = 0; j < 4; ++j)
        #pragma unroll
        for (int e = 0; e < 4; ++e) {
          int row = bm * 128 + wm + i * 16 + quad * 4 + e;
          int col = cb + wn + j * 16 + l16;
          Vb[(size_t)row * D_MODEL + col] = f2bf(acc[i][j][e]);
        }
  }
}

// ---- out GEMM (r7 structure): A reg-staged + S-scale, B DMA-staged ---------
// out[M,1024] = (S(row,head)*V)[M,1024] * Wo[1024,1024]^T.
__global__ __launch_bounds__(256, 4) void gemm_out_kernel(const u16* __restrict__ A,
                                                          const u16* __restrict__ B,
                                                          const float* __restrict__ S,
                                                          float* __restrict__ C) {
  constexpr int K = D_MODEL, N = D_MODEL;
  __shared__ u16 As[2 * BUF];
  __shared__ u16 Bs[2 * BUF];
  const int tid  = threadIdx.x;
  const int lane = tid & 63;
  const int wave = tid >> 6;
  const int wm = (wave >> 1) * 64;
  const int wn = (wave & 1) * 64;
  const int bm = blockIdx.y * 128;
  const int bn = blockIdx.x * 128;
  const int quad = lane >> 4;
  const int l16  = lane & 15;
  const int rchunk = quad ^ ((l16 >> 1) & 3);

  // A: register staging (scale must touch each element exactly once)
  const int lr = tid >> 2;
  const int lch = tid & 3;
  const int wch = lch ^ ((lr >> 1) & 3);
  const u16* Ap0 = A + (size_t)(bm + lr) * K + lch * 8;
  const u16* Ap1 = Ap0 + (size_t)64 * K;
  u16* Aw0 = As + lr * 32 + wch * 8;
  u16* Aw1 = Aw0 + 64 * 32;
  const float* Sp0 = S + (size_t)(bm + lr) * N_HEADS;
  const float* Sp1 = Sp0 + (size_t)64 * N_HEADS;

  // B: DMA staging
  const int srow = lane >> 2;
  const int gch  = (lane & 3) ^ ((lane >> 3) & 3);
  const u16* Bg0 = B + (size_t)(bn + wave * 16 + srow) * K + gch * 8;
  const u16* Bg1 = Bg0 + (size_t)64 * K;
  u16* Bl = Bs + wave * 16 * 32 + lane * 8;

  f32x4 acc[4][4];
  #pragma unroll
  for (int i = 0; i < 4; ++i)
    #pragma unroll
    for (int j = 0; j < 4; ++j) acc[i][j] = (f32x4){0.f, 0.f, 0.f, 0.f};

  // prologue: tile 0 -> buf0 (A scaled via regs, B via DMA); A-regs <- tile 1
  uint4 a0 = *(const uint4*)Ap0;
  uint4 a1 = *(const uint4*)Ap1;
  float rs0 = Sp0[0], rs1 = Sp1[0];
  cp16(Bg0, Bl);           cp16(Bg1, Bl + 64 * 32);
  {
    uint4 w0, w1;
    w0.x = scale2(a0.x, rs0); w0.y = scale2(a0.y, rs0);
    w0.z = scale2(a0.z, rs0); w0.w = scale2(a0.w, rs0);
    w1.x = scale2(a1.x, rs1); w1.y = scale2(a1.y, rs1);
    w1.z = scale2(a1.z, rs1); w1.w = scale2(a1.w, rs1);
    *(uint4*)Aw0 = w0; *(uint4*)Aw1 = w1;
  }
  a0 = *(const uint4*)(Ap0 + 32);
  a1 = *(const uint4*)(Ap1 + 32);
  // scales for tile 1: head = 1>>1 = 0 (rs unchanged)
  __syncthreads();

  #pragma unroll 2
  for (int t = 0; t < NT; ++t) {
    const int p = t & 1;
    const u16* Ar = As + p * BUF;
    const u16* Br = Bs + p * BUF;
    bf16x8 af[4], bfr[4];
    #pragma unroll
    for (int i = 0; i < 4; ++i)
      af[i] = *(const bf16x8*)(Ar + (wm + i * 16 + l16) * 32 + rchunk * 8);
    #pragma unroll
    for (int j = 0; j < 4; ++j)
      bfr[j] = *(const bf16x8*)(Br + (wn + j * 16 + l16) * 32 + rchunk * 8);
    if (t + 1 < NT) {
      const int q = (p ^ 1) * BUF;
      cp16(Bg0 + (t + 1) * 32, Bl + q);
      cp16(Bg1 + (t + 1) * 32, Bl + q + 64 * 32);
      uint4 w0, w1;
      w0.x = scale2(a0.x, rs0); w0.y = scale2(a0.y, rs0);
      w0.z = scale2(a0.z, rs0); w0.w = scale2(a0.w, rs0);
      w1.x = scale2(a1.x, rs1); w1.y = scale2(a1.y, rs1);
      w1.z = scale2(a1.z, rs1); w1.w = scale2(a1.w, rs1);
      *(uint4*)(Aw0 + q) = w0; *(uint4*)(Aw1 + q) = w1;
      if (t + 2 < NT) {  // prefetch A tile t+2 + its scale
        const int o = (t + 2) * 32;
        a0 = *(const uint4*)(Ap0 + o);
        a1 = *(const uint4*)(Ap1 + o);
        rs0 = Sp0[(t + 2) >> 1];
        rs1 = Sp1[(t + 2) >> 1];
      }
    }
    #pragma unroll
    for (int i = 0; i < 4; ++i)
      #pragma unroll
      for (int j = 0; j < 4; ++j)
        acc[i][j] = __builtin_amdgcn_mfma_f32_16x16x32_bf16(af[i], bfr[j], acc[i][j], 0, 0, 0);
    __syncthreads();
  }

  #pragma unroll
  for (int i = 0; i < 4; ++i)
    #pragma unroll
    for (int j = 0; j < 4; ++j)
      #pragma unroll
      for (int e = 0; e < 4; ++e) {
        int row = bm + wm + i * 16 + quad * 4 + e;
        int col = bn + wn + j * 16 + l16;
        C[(size_t)row * N + col] = acc[i][j][e];
      }
}

// ---- launch ----------------------------------------------------------------
extern "C" void kernel_launch(void* const* d_in, const int* in_sizes, int n_in,
                              void* d_out, int out_size, void* d_ws, size_t ws_size,
                              hipStream_t stream) {
  const float* hs = (const float*)d_in[0];
  const float* Wq = (const float*)d_in[3];
  const float* Wk = (const float*)d_in[4];
  const float* Wv = (const float*)d_in[5];
  const float* Wo = (const float*)d_in[6];
  // d_in[1,2,7,8,9] dead (fast-weight state identically zero).

  char* ws = (char*)d_ws;
  u16*  Xb = (u16*)ws;                     // [8192][1024] bf16 (16 MB)
  u16*  Wb = (u16*)(ws + (16u << 20));     // [4096][1024] bf16 qk|v|o (8 MB)
  u16*  Vb = (u16*)(ws + (24u << 20));     // [8192][1024] bf16 (16 MB)
  float* Sb = (float*)(ws + (40u << 20));  // [8192][16] f32 (512 KB)
  float* out = (float*)d_out;

  cast_kernel<<<6144, 256, 0, stream>>>(hs, Wq, Wk, Wv, Wo, Xb, Wb);
  gemm_qkv_kernel<<<dim3(24, 64), 256, 0, stream>>>(Xb, Wb, Vb, Sb);
  gemm_out_kernel<<<dim3(8, 64), 256, 0, stream>>>(
      Vb, Wb + (size_t)3072 * D_MODEL, Sb, out);
}

// Round 4
// 199.587 us; speedup vs baseline: 1.0368x; 1.0368x over previous
//
#include <hip/hip_runtime.h>
#include <hip/hip_bf16.h>
#include <stdint.h>

// CortexBlock — reference collapses (U,V start at 0; update is multiplicative
// in the state, so the fast-weight path is identically 0):
//   y[row,h,:] = sigmoid((q_h.k_h)/8) * v_h ;  out = y @ Wo^T
// Round 12: single-variable fix on the best-measured qkv variant (r10,
// 63.2us): keep 256x128 tile / BK=32 / triple-buffer DMA / counted vmcnt(6)
// exactly, and apply the r11-verified XOR swizzle pair that removes r10's
// measured 4.7M-cycle 8-way bank conflict:
//   - DMA source chunk: gch = (l&3) ^ ((l>>3)&3)  (linear LDS dest, rule #21)
//   - fragment read:    rc  = quad ^ ((l16>>1)&3)
// LDS[r][c] then holds global chunk c ^ ((r>>1)&3); b128 reads land 2
// lanes/16B-slot = free (m136). r11 measured this pair at 0 conflicts.
// cast_kernel / gemm_out_kernel unchanged from round 8.
#define D_MODEL 1024
#define N_HEADS 16
#define D_HEAD  64
#define SEQ_T   2048
#define BATCH   4

typedef unsigned short u16;
typedef __bf16 bf16x8 __attribute__((ext_vector_type(8)));
typedef float  f32x4  __attribute__((ext_vector_type(4)));

#define NT 32          // K tiles for gemm_out (K=1024, BK=32)
#define BUF 4096       // u16 elements per LDS buffer (128*32) for gemm_out
#define QNT 32         // K tiles for gemm_qkv (K=1024, BK=32)

// ---- helpers ---------------------------------------------------------------
__device__ __forceinline__ u16 f2bf(float x) {  // RNE f32->bf16
  unsigned u = __float_as_uint(x);
  u += 0x7fffu + ((u >> 16) & 1u);
  return (u16)(u >> 16);
}
__device__ __forceinline__ unsigned pk2(float a, float b) {
  return (unsigned)f2bf(a) | ((unsigned)f2bf(b) << 16);
}
__device__ __forceinline__ unsigned scale2(unsigned p, float s) {
  float lo = __uint_as_float(p << 16) * s;
  float hi = __uint_as_float(p & 0xffff0000u) * s;
  return pk2(lo, hi);
}
// async global->LDS, 16B per lane; LDS dest must be wave-uniform base+lane*16.
__device__ __forceinline__ void cp16(const u16* g, u16* l) {
  __builtin_amdgcn_global_load_lds(
      (const __attribute__((address_space(1))) unsigned int*)g,
      (__attribute__((address_space(3))) unsigned int*)l, 16, 0, 0);
}

// ---- fused cast fp32 -> bf16 with weight-row remap, 32B/thread -------------
// Wb rows: [0,2048): qk-interleaved: row h*128 + jj*16 + l  (jj=0..7) =
//   (jj odd ? Wk : Wq)[h*64 + (jj>>1)*16 + l];  [2048,3072): Wv; [3072,4096): Wo.
__global__ __launch_bounds__(256) void cast_kernel(const float* __restrict__ hs,
                                                   const float* __restrict__ wq,
                                                   const float* __restrict__ wk,
                                                   const float* __restrict__ wv,
                                                   const float* __restrict__ wo,
                                                   u16* __restrict__ Xb,
                                                   u16* __restrict__ Wb) {
  int g = blockIdx.x * 256 + threadIdx.x;  // 8-float groups; 1.5M total
  const float4* src; uint4* dst;
  if (g < (1 << 20)) {                     // X: 1M groups
    src = (const float4*)hs + 2 * (size_t)g;
    dst = (uint4*)Xb + g;
  } else {
    int j = g - (1 << 20);                 // W: 512K groups, 128 per row
    int R = j >> 7;                        // dest row (block-uniform branch mix ok)
    int col8 = j & 127;
    const float* s;
    int srow;
    if (R < 2048) {
      int h = R >> 7, c = R & 127, jj = c >> 4, l = c & 15;
      srow = h * 64 + (jj >> 1) * 16 + l;
      s = (jj & 1) ? wk : wq;
    } else if (R < 3072) { s = wv; srow = R - 2048; }
    else                 { s = wo; srow = R - 3072; }
    src = (const float4*)s + (size_t)srow * 256 + col8 * 2;
    dst = (uint4*)Wb + (size_t)R * 128 + col8;
  }
  float4 lo = src[0], hi = src[1];
  uint4 o;
  o.x = pk2(lo.x, lo.y); o.y = pk2(lo.z, lo.w);
  o.z = pk2(hi.x, hi.y); o.w = pk2(hi.z, hi.w);
  *dst = o;
}

// ---- QKV GEMM: 256x128 tile, BK=32, triple-buffer DMA, swizzled LDS --------
// C[M, 3072-virtual] = X[M,1024] * Wb[qk|v][.,1024]^T, bf16 operands.
// LDS (u16 idx): A[3][256][32] at 0 (8192/buf), B[3][128][32] at 24576
// (4096/buf).  Stage unit r = 64 rows (A: r=0..3, B: r=0..1), 1 cp16/thread.
// Swizzle: LDS[r][c] holds global chunk c ^ ((r>>1)&3) (16B chunks).
#define QVM(n) asm volatile("s_waitcnt vmcnt(" #n ")" ::: "memory")

__global__ __launch_bounds__(256, 2) void gemm_qkv_kernel(const u16* __restrict__ A,
                                                          const u16* __restrict__ B,
                                                          u16* __restrict__ Vb,
                                                          float* __restrict__ S) {
  __shared__ u16 Ls[36864];  // 72 KiB
  const int tid  = threadIdx.x;
  const int w    = tid >> 6;     // 4 waves
  const int l    = tid & 63;
  const int quad = l >> 4;
  const int l16  = l & 15;
  const int wm   = (w >> 1) * 128;   // wave row offset in 256-row tile
  const int wn   = (w & 1) * 64;     // wave col offset in 128-col tile
  const int rc   = (quad ^ ((l16 >> 1) & 3)) * 8;  // swizzled read chunk (u16)

  // XCD-chunked work remap: launch id -> work id, 768 = 8 chunks * 96.
  const int id  = blockIdx.y * 24 + blockIdx.x;
  const int id2 = (id & 7) * 96 + (id >> 3);
  const int bm  = id2 / 24;          // 0..31 (256-row panel)
  const int bn  = id2 % 24;          // 0..15 score (head bn), 16..23 v

  // ---- staging: pre-swizzled SOURCE, linear LDS dest (rule #21) ----
  const int srow = w * 16 + (l >> 2);              // 0..63 within a 64-row unit
  const int schk = ((l & 3) ^ ((l >> 3) & 3)) * 8; // swizzled src chunk (u16)
  const u16* aS[4]; const u16* bS[2];
  #pragma unroll
  for (int r = 0; r < 4; ++r)
    aS[r] = A + (size_t)(bm * 256 + r * 64 + srow) * 1024 + schk;
  #pragma unroll
  for (int r = 0; r < 2; ++r)
    bS[r] = B + (size_t)(bn * 128 + r * 64 + srow) * 1024 + schk;
  u16* dA = Ls + w * 512 + l * 8;              // + sbuf*8192 + r*2048
  u16* dB = Ls + 24576 + w * 512 + l * 8;      // + sbuf*4096 + r*2048

  f32x4 acc[8][4];
  #pragma unroll
  for (int i = 0; i < 8; ++i)
    #pragma unroll
    for (int j = 0; j < 4; ++j) acc[i][j] = (f32x4){0.f, 0.f, 0.f, 0.f};

  // ---- prologue: stage tiles 0,1; drain tile 0 only ----
  #pragma unroll
  for (int r = 0; r < 4; ++r) cp16(aS[r] + 0 * 32, dA + 0 * 8192 + r * 2048);
  #pragma unroll
  for (int r = 0; r < 2; ++r) cp16(bS[r] + 0 * 32, dB + 0 * 4096 + r * 2048);
  #pragma unroll
  for (int r = 0; r < 4; ++r) cp16(aS[r] + 1 * 32, dA + 1 * 8192 + r * 2048);
  #pragma unroll
  for (int r = 0; r < 2; ++r) cp16(bS[r] + 1 * 32, dB + 1 * 4096 + r * 2048);
  QVM(6);
  __builtin_amdgcn_s_barrier();

  // ---- main loop: 1 K-tile (BK=32) per iteration ----
  int rbuf = 0, sbuf = 2;
  #pragma unroll 1
  for (int t = 0; t < QNT; ++t) {
    if (t + 2 < QNT) {  // stage tile t+2 into sbuf (6 cp16)
      #pragma unroll
      for (int r = 0; r < 4; ++r)
        cp16(aS[r] + (t + 2) * 32, dA + sbuf * 8192 + r * 2048);
      #pragma unroll
      for (int r = 0; r < 2; ++r)
        cp16(bS[r] + (t + 2) * 32, dB + sbuf * 4096 + r * 2048);
    }
    const u16* Ar = Ls + rbuf * 8192;
    const u16* Br = Ls + 24576 + rbuf * 4096;
    bf16x8 af[8], bfr[4];
    #pragma unroll
    for (int i = 0; i < 8; ++i)
      af[i] = *(const bf16x8*)(Ar + (wm + i * 16 + l16) * 32 + rc);
    #pragma unroll
    for (int j = 0; j < 4; ++j)
      bfr[j] = *(const bf16x8*)(Br + (wn + j * 16 + l16) * 32 + rc);
    __builtin_amdgcn_s_setprio(1);
    #pragma unroll
    for (int i = 0; i < 8; ++i)
      #pragma unroll
      for (int j = 0; j < 4; ++j)
        acc[i][j] = __builtin_amdgcn_mfma_f32_16x16x32_bf16(af[i], bfr[j], acc[i][j], 0, 0, 0);
    __builtin_amdgcn_s_setprio(0);
    if (t + 2 < QNT) { QVM(6); } else { QVM(0); }
    __builtin_amdgcn_s_barrier();
    rbuf = (rbuf == 2) ? 0 : rbuf + 1;
    sbuf = (sbuf == 2) ? 0 : sbuf + 1;
  }

  // ---- epilogue ----
  if (bn < 16) {
    // one head per block (head bn): col c -> jj = c>>4 = (w&1)*4 + j;
    // (q,k) pairs are (j even, j odd) within the wave.
    float part[8][4];
    #pragma unroll
    for (int i = 0; i < 8; ++i)
      #pragma unroll
      for (int e = 0; e < 4; ++e)
        part[i][e] = acc[i][0][e] * acc[i][1][e] + acc[i][2][e] * acc[i][3][e];
    #pragma unroll
    for (int m = 1; m <= 8; m <<= 1)
      #pragma unroll
      for (int i = 0; i < 8; ++i)
        #pragma unroll
        for (int e = 0; e < 4; ++e)
          part[i][e] += __shfl_xor(part[i][e], m);  // reduce over l16 (d-low)
    float* Sp = (float*)Ls;  // [256][2] f32
    if (l16 == 0) {
      #pragma unroll
      for (int i = 0; i < 8; ++i)
        #pragma unroll
        for (int e = 0; e < 4; ++e)
          Sp[(wm + i * 16 + quad * 4 + e) * 2 + (w & 1)] = part[i][e];
    }
    __syncthreads();
    {
      int row = tid;  // 256 threads = 256 rows
      float s = (Sp[row * 2] + Sp[row * 2 + 1]) * 0.125f;  // 1/sqrt(64)
      S[(size_t)(bm * 256 + row) * N_HEADS + bn] = 1.f / (1.f + __expf(-s));
    }
  } else {
    const int cb = (bn - 16) * 128;
    #pragma unroll
    for (int i = 0; i < 8; ++i)
      #pragma unroll
      for (int j = 0; j < 4; ++j)
        #pragma unroll
        for (int e = 0; e < 4; ++e) {
          int row = bm * 256 + wm + i * 16 + quad * 4 + e;
          int col = cb + wn + j * 16 + l16;
          Vb[(size_t)row * D_MODEL + col] = f2bf(acc[i][j][e]);
        }
  }
}

// ---- out GEMM (r7 structure): A reg-staged + S-scale, B DMA-staged ---------
// out[M,1024] = (S(row,head)*V)[M,1024] * Wo[1024,1024]^T.
__global__ __launch_bounds__(256, 4) void gemm_out_kernel(const u16* __restrict__ A,
                                                          const u16* __restrict__ B,
                                                          const float* __restrict__ S,
                                                          float* __restrict__ C) {
  constexpr int K = D_MODEL, N = D_MODEL;
  __shared__ u16 As[2 * BUF];
  __shared__ u16 Bs[2 * BUF];
  const int tid  = threadIdx.x;
  const int lane = tid & 63;
  const int wave = tid >> 6;
  const int wm = (wave >> 1) * 64;
  const int wn = (wave & 1) * 64;
  const int bm = blockIdx.y * 128;
  const int bn = blockIdx.x * 128;
  const int quad = lane >> 4;
  const int l16  = lane & 15;
  const int rchunk = quad ^ ((l16 >> 1) & 3);

  // A: register staging (scale must touch each element exactly once)
  const int lr = tid >> 2;
  const int lch = tid & 3;
  const int wch = lch ^ ((lr >> 1) & 3);
  const u16* Ap0 = A + (size_t)(bm + lr) * K + lch * 8;
  const u16* Ap1 = Ap0 + (size_t)64 * K;
  u16* Aw0 = As + lr * 32 + wch * 8;
  u16* Aw1 = Aw0 + 64 * 32;
  const float* Sp0 = S + (size_t)(bm + lr) * N_HEADS;
  const float* Sp1 = Sp0 + (size_t)64 * N_HEADS;

  // B: DMA staging
  const int srow = lane >> 2;
  const int gch  = (lane & 3) ^ ((lane >> 3) & 3);
  const u16* Bg0 = B + (size_t)(bn + wave * 16 + srow) * K + gch * 8;
  const u16* Bg1 = Bg0 + (size_t)64 * K;
  u16* Bl = Bs + wave * 16 * 32 + lane * 8;

  f32x4 acc[4][4];
  #pragma unroll
  for (int i = 0; i < 4; ++i)
    #pragma unroll
    for (int j = 0; j < 4; ++j) acc[i][j] = (f32x4){0.f, 0.f, 0.f, 0.f};

  // prologue: tile 0 -> buf0 (A scaled via regs, B via DMA); A-regs <- tile 1
  uint4 a0 = *(const uint4*)Ap0;
  uint4 a1 = *(const uint4*)Ap1;
  float rs0 = Sp0[0], rs1 = Sp1[0];
  cp16(Bg0, Bl);           cp16(Bg1, Bl + 64 * 32);
  {
    uint4 w0, w1;
    w0.x = scale2(a0.x, rs0); w0.y = scale2(a0.y, rs0);
    w0.z = scale2(a0.z, rs0); w0.w = scale2(a0.w, rs0);
    w1.x = scale2(a1.x, rs1); w1.y = scale2(a1.y, rs1);
    w1.z = scale2(a1.z, rs1); w1.w = scale2(a1.w, rs1);
    *(uint4*)Aw0 = w0; *(uint4*)Aw1 = w1;
  }
  a0 = *(const uint4*)(Ap0 + 32);
  a1 = *(const uint4*)(Ap1 + 32);
  // scales for tile 1: head = 1>>1 = 0 (rs unchanged)
  __syncthreads();

  #pragma unroll 2
  for (int t = 0; t < NT; ++t) {
    const int p = t & 1;
    const u16* Ar = As + p * BUF;
    const u16* Br = Bs + p * BUF;
    bf16x8 af[4], bfr[4];
    #pragma unroll
    for (int i = 0; i < 4; ++i)
      af[i] = *(const bf16x8*)(Ar + (wm + i * 16 + l16) * 32 + rchunk * 8);
    #pragma unroll
    for (int j = 0; j < 4; ++j)
      bfr[j] = *(const bf16x8*)(Br + (wn + j * 16 + l16) * 32 + rchunk * 8);
    if (t + 1 < NT) {
      const int q = (p ^ 1) * BUF;
      cp16(Bg0 + (t + 1) * 32, Bl + q);
      cp16(Bg1 + (t + 1) * 32, Bl + q + 64 * 32);
      uint4 w0, w1;
      w0.x = scale2(a0.x, rs0); w0.y = scale2(a0.y, rs0);
      w0.z = scale2(a0.z, rs0); w0.w = scale2(a0.w, rs0);
      w1.x = scale2(a1.x, rs1); w1.y = scale2(a1.y, rs1);
      w1.z = scale2(a1.z, rs1); w1.w = scale2(a1.w, rs1);
      *(uint4*)(Aw0 + q) = w0; *(uint4*)(Aw1 + q) = w1;
      if (t + 2 < NT) {  // prefetch A tile t+2 + its scale
        const int o = (t + 2) * 32;
        a0 = *(const uint4*)(Ap0 + o);
        a1 = *(const uint4*)(Ap1 + o);
        rs0 = Sp0[(t + 2) >> 1];
        rs1 = Sp1[(t + 2) >> 1];
      }
    }
    #pragma unroll
    for (int i = 0; i < 4; ++i)
      #pragma unroll
      for (int j = 0; j < 4; ++j)
        acc[i][j] = __builtin_amdgcn_mfma_f32_16x16x32_bf16(af[i], bfr[j], acc[i][j], 0, 0, 0);
    __syncthreads();
  }

  #pragma unroll
  for (int i = 0; i < 4; ++i)
    #pragma unroll
    for (int j = 0; j < 4; ++j)
      #pragma unroll
      for (int e = 0; e < 4; ++e) {
        int row = bm + wm + i * 16 + quad * 4 + e;
        int col = bn + wn + j * 16 + l16;
        C[(size_t)row * N + col] = acc[i][j][e];
      }
}

// ---- launch ----------------------------------------------------------------
extern "C" void kernel_launch(void* const* d_in, const int* in_sizes, int n_in,
                              void* d_out, int out_size, void* d_ws, size_t ws_size,
                              hipStream_t stream) {
  const float* hs = (const float*)d_in[0];
  const float* Wq = (const float*)d_in[3];
  const float* Wk = (const float*)d_in[4];
  const float* Wv = (const float*)d_in[5];
  const float* Wo = (const float*)d_in[6];
  // d_in[1,2,7,8,9] dead (fast-weight state identically zero).

  char* ws = (char*)d_ws;
  u16*  Xb = (u16*)ws;                     // [8192][1024] bf16 (16 MB)
  u16*  Wb = (u16*)(ws + (16u << 20));     // [4096][1024] bf16 qk|v|o (8 MB)
  u16*  Vb = (u16*)(ws + (24u << 20));     // [8192][1024] bf16 (16 MB)
  float* Sb = (float*)(ws + (40u << 20));  // [8192][16] f32 (512 KB)
  float* out = (float*)d_out;

  cast_kernel<<<6144, 256, 0, stream>>>(hs, Wq, Wk, Wv, Wo, Xb, Wb);
  gemm_qkv_kernel<<<dim3(24, 32), 256, 0, stream>>>(Xb, Wb, Vb, Sb);
  gemm_out_kernel<<<dim3(8, 64), 256, 0, stream>>>(
      Vb, Wb + (size_t)3072 * D_MODEL, Sb, out);
}

// Round 5
// 189.552 us; speedup vs baseline: 1.0917x; 1.0529x over previous
//
#include <hip/hip_runtime.h>
#include <hip/hip_bf16.h>
#include <stdint.h>

// CortexBlock — reference collapses (U,V start at 0; update is multiplicative
// in the state, so the fast-weight path is identically 0):
//   y[row,h,:] = sigmoid((q_h.k_h)/8) * v_h ;  out = y @ Wo^T
// Round 13: qkv reverted to r10 verbatim (best measured: 63.2us / best total
// 198.8us; r12 proved its 4.7M bank conflicts are NOT on the critical path —
// removing them cost 10%). This round attacks the unmeasured remainder:
//  - gemm_out scale2 now uses v_cvt_pk_bf16_f32 (1 inst packs 2 RNE converts;
//    was ~13 VALU ops manual) — out's A-staging was ~104 VALU/thread/tile,
//    comparable to its MFMA time (VALU-bound staging pattern).
//  - gemm_out XCD-chunked block remap: each XCD now covers 8 bm-panels x all
//    8 bn (A 2MB + B 2MB = L2-fit) instead of streaming 16MB of A from L3.
// cast_kernel unchanged (memory-bound; manual RNE kept there).
#define D_MODEL 1024
#define N_HEADS 16
#define D_HEAD  64
#define SEQ_T   2048
#define BATCH   4

typedef unsigned short u16;
typedef __bf16 bf16x8 __attribute__((ext_vector_type(8)));
typedef float  f32x4  __attribute__((ext_vector_type(4)));

#define NT 32          // K tiles for gemm_out (K=1024, BK=32)
#define BUF 4096       // u16 elements per LDS buffer (128*32) for gemm_out
#define QNT 32         // K tiles for gemm_qkv (K=1024, BK=32)

// ---- helpers ---------------------------------------------------------------
__device__ __forceinline__ u16 f2bf(float x) {  // RNE f32->bf16
  unsigned u = __float_as_uint(x);
  u += 0x7fffu + ((u >> 16) & 1u);
  return (u16)(u >> 16);
}
__device__ __forceinline__ unsigned pk2(float a, float b) {
  return (unsigned)f2bf(a) | ((unsigned)f2bf(b) << 16);
}
// scale packed bf16 pair by s; repack via HW RNE packed convert (T12).
__device__ __forceinline__ unsigned scale2(unsigned p, float s) {
  float lo = __uint_as_float(p << 16) * s;
  float hi = __uint_as_float(p & 0xffff0000u) * s;
  unsigned r;
  asm("v_cvt_pk_bf16_f32 %0, %1, %2" : "=v"(r) : "v"(lo), "v"(hi));
  return r;
}
// async global->LDS, 16B per lane; LDS dest must be wave-uniform base+lane*16.
__device__ __forceinline__ void cp16(const u16* g, u16* l) {
  __builtin_amdgcn_global_load_lds(
      (const __attribute__((address_space(1))) unsigned int*)g,
      (__attribute__((address_space(3))) unsigned int*)l, 16, 0, 0);
}

// ---- fused cast fp32 -> bf16 with weight-row remap, 32B/thread -------------
// Wb rows: [0,2048): qk-interleaved: row h*128 + jj*16 + l  (jj=0..7) =
//   (jj odd ? Wk : Wq)[h*64 + (jj>>1)*16 + l];  [2048,3072): Wv; [3072,4096): Wo.
__global__ __launch_bounds__(256) void cast_kernel(const float* __restrict__ hs,
                                                   const float* __restrict__ wq,
                                                   const float* __restrict__ wk,
                                                   const float* __restrict__ wv,
                                                   const float* __restrict__ wo,
                                                   u16* __restrict__ Xb,
                                                   u16* __restrict__ Wb) {
  int g = blockIdx.x * 256 + threadIdx.x;  // 8-float groups; 1.5M total
  const float4* src; uint4* dst;
  if (g < (1 << 20)) {                     // X: 1M groups
    src = (const float4*)hs + 2 * (size_t)g;
    dst = (uint4*)Xb + g;
  } else {
    int j = g - (1 << 20);                 // W: 512K groups, 128 per row
    int R = j >> 7;                        // dest row (block-uniform branch mix ok)
    int col8 = j & 127;
    const float* s;
    int srow;
    if (R < 2048) {
      int h = R >> 7, c = R & 127, jj = c >> 4, l = c & 15;
      srow = h * 64 + (jj >> 1) * 16 + l;
      s = (jj & 1) ? wk : wq;
    } else if (R < 3072) { s = wv; srow = R - 2048; }
    else                 { s = wo; srow = R - 3072; }
    src = (const float4*)s + (size_t)srow * 256 + col8 * 2;
    dst = (uint4*)Wb + (size_t)R * 128 + col8;
  }
  float4 lo = src[0], hi = src[1];
  uint4 o;
  o.x = pk2(lo.x, lo.y); o.y = pk2(lo.z, lo.w);
  o.z = pk2(hi.x, hi.y); o.w = pk2(hi.z, hi.w);
  *dst = o;
}

// ---- QKV GEMM: 256x128 tile, BK=32, triple-buffer DMA, counted vmcnt -------
// (r10 verbatim — best measured 63.2us; its 4.7M LDS conflicts are hidden
// under cross-block overlap, r12 measured removing them at -10%.)
// C[M, 3072-virtual] = X[M,1024] * Wb[qk|v][.,1024]^T, bf16 operands.
// LDS (u16 idx): A[3][256][32] at 0 (8192/buf), B[3][128][32] at 24576
// (4096/buf).  Stage unit r = 64 rows (A: r=0..3, B: r=0..1), 1 cp16/thread.
#define QVM(n) asm volatile("s_waitcnt vmcnt(" #n ")" ::: "memory")

__global__ __launch_bounds__(256, 2) void gemm_qkv_kernel(const u16* __restrict__ A,
                                                          const u16* __restrict__ B,
                                                          u16* __restrict__ Vb,
                                                          float* __restrict__ S) {
  __shared__ u16 Ls[36864];  // 72 KiB
  const int tid  = threadIdx.x;
  const int w    = tid >> 6;     // 4 waves
  const int l    = tid & 63;
  const int quad = l >> 4;
  const int l16  = l & 15;
  const int wm   = (w >> 1) * 128;   // wave row offset in 256-row tile
  const int wn   = (w & 1) * 64;     // wave col offset in 128-col tile

  // XCD-chunked work remap: launch id -> work id, 768 = 8 chunks * 96.
  const int id  = blockIdx.y * 24 + blockIdx.x;
  const int id2 = (id & 7) * 96 + (id >> 3);
  const int bm  = id2 / 24;          // 0..31 (256-row panel)
  const int bn  = id2 % 24;          // 0..15 score (head bn), 16..23 v

  // ---- staging addresses (all linear; 1 cp16/thread per 64-row unit) ----
  const int srow = w * 16 + (l >> 2);          // 0..63 within a 64-row unit
  const int schk = (l & 3) * 8;                // k-chunk (u16)
  const u16* aS[4]; const u16* bS[2];
  #pragma unroll
  for (int r = 0; r < 4; ++r)
    aS[r] = A + (size_t)(bm * 256 + r * 64 + srow) * 1024 + schk;
  #pragma unroll
  for (int r = 0; r < 2; ++r)
    bS[r] = B + (size_t)(bn * 128 + r * 64 + srow) * 1024 + schk;
  u16* dA = Ls + w * 512 + l * 8;              // + sbuf*8192 + r*2048
  u16* dB = Ls + 24576 + w * 512 + l * 8;      // + sbuf*4096 + r*2048

  f32x4 acc[8][4];
  #pragma unroll
  for (int i = 0; i < 8; ++i)
    #pragma unroll
    for (int j = 0; j < 4; ++j) acc[i][j] = (f32x4){0.f, 0.f, 0.f, 0.f};

  // ---- prologue: stage tiles 0,1; drain tile 0 only ----
  #pragma unroll
  for (int r = 0; r < 4; ++r) cp16(aS[r] + 0 * 32, dA + 0 * 8192 + r * 2048);
  #pragma unroll
  for (int r = 0; r < 2; ++r) cp16(bS[r] + 0 * 32, dB + 0 * 4096 + r * 2048);
  #pragma unroll
  for (int r = 0; r < 4; ++r) cp16(aS[r] + 1 * 32, dA + 1 * 8192 + r * 2048);
  #pragma unroll
  for (int r = 0; r < 2; ++r) cp16(bS[r] + 1 * 32, dB + 1 * 4096 + r * 2048);
  QVM(6);
  __builtin_amdgcn_s_barrier();

  // ---- main loop: 1 K-tile (BK=32) per iteration ----
  int rbuf = 0, sbuf = 2;
  #pragma unroll 1
  for (int t = 0; t < QNT; ++t) {
    if (t + 2 < QNT) {  // stage tile t+2 into sbuf (6 cp16)
      #pragma unroll
      for (int r = 0; r < 4; ++r)
        cp16(aS[r] + (t + 2) * 32, dA + sbuf * 8192 + r * 2048);
      #pragma unroll
      for (int r = 0; r < 2; ++r)
        cp16(bS[r] + (t + 2) * 32, dB + sbuf * 4096 + r * 2048);
    }
    const u16* Ar = Ls + rbuf * 8192;
    const u16* Br = Ls + 24576 + rbuf * 4096;
    bf16x8 af[8], bfr[4];
    #pragma unroll
    for (int i = 0; i < 8; ++i)
      af[i] = *(const bf16x8*)(Ar + (wm + i * 16 + l16) * 32 + quad * 8);
    #pragma unroll
    for (int j = 0; j < 4; ++j)
      bfr[j] = *(const bf16x8*)(Br + (wn + j * 16 + l16) * 32 + quad * 8);
    __builtin_amdgcn_s_setprio(1);
    #pragma unroll
    for (int i = 0; i < 8; ++i)
      #pragma unroll
      for (int j = 0; j < 4; ++j)
        acc[i][j] = __builtin_amdgcn_mfma_f32_16x16x32_bf16(af[i], bfr[j], acc[i][j], 0, 0, 0);
    __builtin_amdgcn_s_setprio(0);
    if (t + 2 < QNT) { QVM(6); } else { QVM(0); }
    __builtin_amdgcn_s_barrier();
    rbuf = (rbuf == 2) ? 0 : rbuf + 1;
    sbuf = (sbuf == 2) ? 0 : sbuf + 1;
  }

  // ---- epilogue ----
  if (bn < 16) {
    // one head per block (head bn): col c -> jj = c>>4 = (w&1)*4 + j;
    // (q,k) pairs are (j even, j odd) within the wave.
    float part[8][4];
    #pragma unroll
    for (int i = 0; i < 8; ++i)
      #pragma unroll
      for (int e = 0; e < 4; ++e)
        part[i][e] = acc[i][0][e] * acc[i][1][e] + acc[i][2][e] * acc[i][3][e];
    #pragma unroll
    for (int m = 1; m <= 8; m <<= 1)
      #pragma unroll
      for (int i = 0; i < 8; ++i)
        #pragma unroll
        for (int e = 0; e < 4; ++e)
          part[i][e] += __shfl_xor(part[i][e], m);  // reduce over l16 (d-low)
    float* Sp = (float*)Ls;  // [256][2] f32
    if (l16 == 0) {
      #pragma unroll
      for (int i = 0; i < 8; ++i)
        #pragma unroll
        for (int e = 0; e < 4; ++e)
          Sp[(wm + i * 16 + quad * 4 + e) * 2 + (w & 1)] = part[i][e];
    }
    __syncthreads();
    {
      int row = tid;  // 256 threads = 256 rows
      float s = (Sp[row * 2] + Sp[row * 2 + 1]) * 0.125f;  // 1/sqrt(64)
      S[(size_t)(bm * 256 + row) * N_HEADS + bn] = 1.f / (1.f + __expf(-s));
    }
  } else {
    const int cb = (bn - 16) * 128;
    #pragma unroll
    for (int i = 0; i < 8; ++i)
      #pragma unroll
      for (int j = 0; j < 4; ++j)
        #pragma unroll
        for (int e = 0; e < 4; ++e) {
          int row = bm * 256 + wm + i * 16 + quad * 4 + e;
          int col = cb + wn + j * 16 + l16;
          Vb[(size_t)row * D_MODEL + col] = f2bf(acc[i][j][e]);
        }
  }
}

// ---- out GEMM (r7 structure): A reg-staged + S-scale, B DMA-staged ---------
// out[M,1024] = (S(row,head)*V)[M,1024] * Wo[1024,1024]^T.
// r13: scale2 via v_cvt_pk_bf16_f32 (halves staging VALU); XCD-chunked
// remap (512 = 8 chunks * 64: 8 bm-panels + all bn per XCD -> A+B L2-fit).
__global__ __launch_bounds__(256, 4) void gemm_out_kernel(const u16* __restrict__ A,
                                                          const u16* __restrict__ B,
                                                          const float* __restrict__ S,
                                                          float* __restrict__ C) {
  constexpr int K = D_MODEL, N = D_MODEL;
  __shared__ u16 As[2 * BUF];
  __shared__ u16 Bs[2 * BUF];
  const int tid  = threadIdx.x;
  const int lane = tid & 63;
  const int wave = tid >> 6;
  const int wm = (wave >> 1) * 64;
  const int wn = (wave & 1) * 64;
  const int quad = lane >> 4;
  const int l16  = lane & 15;
  const int rchunk = quad ^ ((l16 >> 1) & 3);

  // XCD-chunked remap: id -> id2, 512 = 8 chunks * 64 (8 bm-panels x 8 bn).
  const int id  = blockIdx.y * 8 + blockIdx.x;
  const int id2 = (id & 7) * 64 + (id >> 3);
  const int bm = (id2 >> 3) * 128;
  const int bn = (id2 & 7) * 128;

  // A: register staging (scale must touch each element exactly once)
  const int lr = tid >> 2;
  const int lch = tid & 3;
  const int wch = lch ^ ((lr >> 1) & 3);
  const u16* Ap0 = A + (size_t)(bm + lr) * K + lch * 8;
  const u16* Ap1 = Ap0 + (size_t)64 * K;
  u16* Aw0 = As + lr * 32 + wch * 8;
  u16* Aw1 = Aw0 + 64 * 32;
  const float* Sp0 = S + (size_t)(bm + lr) * N_HEADS;
  const float* Sp1 = Sp0 + (size_t)64 * N_HEADS;

  // B: DMA staging
  const int srow = lane >> 2;
  const int gch  = (lane & 3) ^ ((lane >> 3) & 3);
  const u16* Bg0 = B + (size_t)(bn + wave * 16 + srow) * K + gch * 8;
  const u16* Bg1 = Bg0 + (size_t)64 * K;
  u16* Bl = Bs + wave * 16 * 32 + lane * 8;

  f32x4 acc[4][4];
  #pragma unroll
  for (int i = 0; i < 4; ++i)
    #pragma unroll
    for (int j = 0; j < 4; ++j) acc[i][j] = (f32x4){0.f, 0.f, 0.f, 0.f};

  // prologue: tile 0 -> buf0 (A scaled via regs, B via DMA); A-regs <- tile 1
  uint4 a0 = *(const uint4*)Ap0;
  uint4 a1 = *(const uint4*)Ap1;
  float rs0 = Sp0[0], rs1 = Sp1[0];
  cp16(Bg0, Bl);           cp16(Bg1, Bl + 64 * 32);
  {
    uint4 w0, w1;
    w0.x = scale2(a0.x, rs0); w0.y = scale2(a0.y, rs0);
    w0.z = scale2(a0.z, rs0); w0.w = scale2(a0.w, rs0);
    w1.x = scale2(a1.x, rs1); w1.y = scale2(a1.y, rs1);
    w1.z = scale2(a1.z, rs1); w1.w = scale2(a1.w, rs1);
    *(uint4*)Aw0 = w0; *(uint4*)Aw1 = w1;
  }
  a0 = *(const uint4*)(Ap0 + 32);
  a1 = *(const uint4*)(Ap1 + 32);
  // scales for tile 1: head = 1>>1 = 0 (rs unchanged)
  __syncthreads();

  #pragma unroll 2
  for (int t = 0; t < NT; ++t) {
    const int p = t & 1;
    const u16* Ar = As + p * BUF;
    const u16* Br = Bs + p * BUF;
    bf16x8 af[4], bfr[4];
    #pragma unroll
    for (int i = 0; i < 4; ++i)
      af[i] = *(const bf16x8*)(Ar + (wm + i * 16 + l16) * 32 + rchunk * 8);
    #pragma unroll
    for (int j = 0; j < 4; ++j)
      bfr[j] = *(const bf16x8*)(Br + (wn + j * 16 + l16) * 32 + rchunk * 8);
    if (t + 1 < NT) {
      const int q = (p ^ 1) * BUF;
      cp16(Bg0 + (t + 1) * 32, Bl + q);
      cp16(Bg1 + (t + 1) * 32, Bl + q + 64 * 32);
      uint4 w0, w1;
      w0.x = scale2(a0.x, rs0); w0.y = scale2(a0.y, rs0);
      w0.z = scale2(a0.z, rs0); w0.w = scale2(a0.w, rs0);
      w1.x = scale2(a1.x, rs1); w1.y = scale2(a1.y, rs1);
      w1.z = scale2(a1.z, rs1); w1.w = scale2(a1.w, rs1);
      *(uint4*)(Aw0 + q) = w0; *(uint4*)(Aw1 + q) = w1;
      if (t + 2 < NT) {  // prefetch A tile t+2 + its scale
        const int o = (t + 2) * 32;
        a0 = *(const uint4*)(Ap0 + o);
        a1 = *(const uint4*)(Ap1 + o);
        rs0 = Sp0[(t + 2) >> 1];
        rs1 = Sp1[(t + 2) >> 1];
      }
    }
    #pragma unroll
    for (int i = 0; i < 4; ++i)
      #pragma unroll
      for (int j = 0; j < 4; ++j)
        acc[i][j] = __builtin_amdgcn_mfma_f32_16x16x32_bf16(af[i], bfr[j], acc[i][j], 0, 0, 0);
    __syncthreads();
  }

  #pragma unroll
  for (int i = 0; i < 4; ++i)
    #pragma unroll
    for (int j = 0; j < 4; ++j)
      #pragma unroll
      for (int e = 0; e < 4; ++e) {
        int row = bm + wm + i * 16 + quad * 4 + e;
        int col = bn + wn + j * 16 + l16;
        C[(size_t)row * N + col] = acc[i][j][e];
      }
}

// ---- launch ----------------------------------------------------------------
extern "C" void kernel_launch(void* const* d_in, const int* in_sizes, int n_in,
                              void* d_out, int out_size, void* d_ws, size_t ws_size,
                              hipStream_t stream) {
  const float* hs = (const float*)d_in[0];
  const float* Wq = (const float*)d_in[3];
  const float* Wk = (const float*)d_in[4];
  const float* Wv = (const float*)d_in[5];
  const float* Wo = (const float*)d_in[6];
  // d_in[1,2,7,8,9] dead (fast-weight state identically zero).

  char* ws = (char*)d_ws;
  u16*  Xb = (u16*)ws;                     // [8192][1024] bf16 (16 MB)
  u16*  Wb = (u16*)(ws + (16u << 20));     // [4096][1024] bf16 qk|v|o (8 MB)
  u16*  Vb = (u16*)(ws + (24u << 20));     // [8192][1024] bf16 (16 MB)
  float* Sb = (float*)(ws + (40u << 20));  // [8192][16] f32 (512 KB)
  float* out = (float*)d_out;

  cast_kernel<<<6144, 256, 0, stream>>>(hs, Wq, Wk, Wv, Wo, Xb, Wb);
  gemm_qkv_kernel<<<dim3(24, 32), 256, 0, stream>>>(Xb, Wb, Vb, Sb);
  gemm_out_kernel<<<dim3(8, 64), 256, 0, stream>>>(
      Vb, Wb + (size_t)3072 * D_MODEL, Sb, out);
}